// Round 4
// baseline (852.656 us; speedup 1.0000x reference)
//
#include <hip/hip_runtime.h>

// HPCrnn R4: barrier-free wave-private recurrence + i8 MFMA (16x16x64).
// Each wave owns 16 batch rows for all 100 steps: no __syncthreads in the time
// loop -> waves drift apart and MFMA/VALU overlap across waves (m114).
// Weights quantized to i8 in LDS (single shared copy, 128 KB = only way two
// 256x256 matrices fit); i8 MFMA = 2x bf16 rate -> matrix floor ~218 us.
// XOR-swizzled LDS layouts: A-frag reads are ds_read_b128 with immediate
// offsets (zero per-read VALU), 2-way-max bank aliasing (free per m136).
// Per-step tables A=basal*c_t, E=A-bias*c_t+0.5 precomputed in lane layout.

typedef int   i32x4 __attribute__((ext_vector_type(4)));
typedef float f32x4 __attribute__((ext_vector_type(4)));
typedef float f32x2 __attribute__((ext_vector_type(2)));

// basal tables: lane-layout index for feature f: quad=(f>>2)&3, mc=f>>4, r=f&3
__global__ void basal2_kernel(const float* __restrict__ Wbasal,
                              const float* __restrict__ bias,
                              float* __restrict__ Atab, float* __restrict__ Etab,
                              float* __restrict__ ctab) {
    const int t = blockIdx.x;      // 0..99 -> x = t+1
    const int n = threadIdx.x;     // 0..255
    __shared__ float ca3s[256];
    __shared__ float red[256];
    const float x = (float)(t + 1);
    const float c0 = (float)n * (100.0f / 255.0f);
    const float d = (x - c0) * 0.2f;
    ca3s[n] = expf(-0.5f * d * d);
    __syncthreads();
    float bas = 0.f;
    #pragma unroll 8
    for (int k = 0; k < 256; ++k) bas += ca3s[k] * Wbasal[k * 256 + n];
    red[n] = bas;
    __syncthreads();
    for (int s = 128; s > 0; s >>= 1) {
        if (n < s) red[n] = fmaxf(red[n], red[n + s]);
        __syncthreads();
    }
    const float bmax = red[0];                 // ca1 < 2*bmax (sigmoid<1, relu)
    const float cq = 127.0f / (2.0f * bmax);   // ca1 quant scale
    const int idx = t * 256 + ((n >> 2) & 3) * 64 + (n >> 4) * 4 + (n & 3);
    const float A = bas * cq;
    Atab[idx] = A;
    Etab[idx] = A - bias[n] * cq + 0.5f;       // +0.5 folds round-to-nearest
    if (n == 0) ctab[t] = (2.0f * bmax) / 127.0f;   // 1/cq
}

__global__ __launch_bounds__(512, 2) void rnn_kernel(
    const float* __restrict__ cue, const float* __restrict__ ec5_init,
    const float* __restrict__ Wap, const float* __restrict__ Wc,
    const float* __restrict__ Wact,
    const float* __restrict__ Atab, const float* __restrict__ Etab,
    const float* __restrict__ ctab, float* __restrict__ out)
{
    __shared__ __align__(16) char smem[163840];   // 64K qWap | 64K qWc | 8x4K scratch
    const int tid  = threadIdx.x;
    const int wave = tid >> 6;
    const int lane = tid & 63;
    const int quad = lane >> 4;
    const int L    = lane & 15;
    const int grow = blockIdx.x * 128 + wave * 16 + L;   // this lane's batch row

    // ---------- preload: per-tensor weight maxima ----------
    float mx1 = 0.f, mx2 = 0.f;
    for (int j = tid; j < 65536; j += 512) {
        mx1 = fmaxf(mx1, Wap[j]);            // Wap >= 0
        mx2 = fmaxf(mx2, fabsf(Wc[j]));
    }
    #pragma unroll
    for (int o = 1; o < 64; o <<= 1) {
        mx1 = fmaxf(mx1, __shfl_xor(mx1, o));
        mx2 = fmaxf(mx2, __shfl_xor(mx2, o));
    }
    float* red = (float*)&smem[131072];
    if (lane == 0) { red[wave] = mx1; red[8 + wave] = mx2; }
    __syncthreads();
    float sW1 = red[0], sW2 = red[8];
    #pragma unroll
    for (int w = 1; w < 8; ++w) {
        sW1 = fmaxf(sW1, red[w]);
        sW2 = fmaxf(sW2, red[8 + w]);
    }
    __syncthreads();
    // ---------- quantize weights into LDS (XOR-swizzled A-frag layout) ----------
    // qW[m][k] stored at m*256 + (((k>>4) ^ (m&15))<<4) + (k&15)
    const float q1 = 127.0f / sW1, q2 = 127.0f / sW2;
    char* qWap = smem;
    char* qWc  = smem + 65536;
    for (int j = tid; j < 65536; j += 512) {
        const int k = j >> 8, m = j & 255;   // W is [k][m] row-major
        const int ad = m * 256 + ((((k >> 4) ^ (m & 15)) & 15) << 4) + (k & 15);
        qWap[ad] = (char)(int)rintf(Wap[j] * q1);
        qWc[ad]  = (char)(int)rintf(Wc[j] * q2);
    }
    __syncthreads();   // last barrier — none inside the time loop

    const float f1     = sW1 / (127.0f * 127.0f);   // gemm1 dequant (ec3 scale 127)
    const float negf1  = -f1;
    const float sWc127 = sW2 / 127.0f;

    // ---------- state: lane holds row grow, features f = mc*16 + quad*4 + r ----------
    float e5[64], e3[64];
    #pragma unroll
    for (int mc = 0; mc < 16; ++mc) {
        const f32x4 v = *(const f32x4*)&ec5_init[grow * 256 + mc * 16 + quad * 4];
        #pragma unroll
        for (int r = 0; r < 4; ++r) { e5[4 * mc + r] = v[r]; e3[4 * mc + r] = 0.f; }
    }

    // ---------- LDS addresses ----------
    const int scr = 131072 + wave * 4096;   // per-wave state scratch (16 rows x 256B)
    int rdv[4], rdw[4], rds[4], wr[16];
    #pragma unroll
    for (int c = 0; c < 4; ++c) {
        const int b = L * 256 + ((((c * 4 + quad) ^ L) & 15) << 4);
        rdv[c] = b;            // qWap A-frag vaddr (+ mc*4096 imm)
        rdw[c] = b + 65536;    // qWc  A-frag vaddr
        rds[c] = b + scr;      // scratch B-frag vaddr
    }
    #pragma unroll
    for (int mc = 0; mc < 16; ++mc)
        wr[mc] = scr + L * 256 + (((mc ^ L) & 15) << 4) + quad * 4;

    // ================= t = 0 (peeled): ec3=0 -> sigmoid = 0.5 exactly =================
    {
        const float f2 = ctab[0] * sWc127;
        const float* Ab = &Atab[quad * 64];
        const float* Eb = &Etab[quad * 64];
        #pragma unroll
        for (int mc = 0; mc < 16; ++mc) {
            const f32x4 av = *(const f32x4*)&Ab[mc * 4];
            const f32x4 ev = *(const f32x4*)&Eb[mc * 4];
            unsigned dw = 0;
            #pragma unroll
            for (int r = 0; r < 4; ++r) {
                const float val = fmaxf(fmaf(av[r], 0.5f, ev[r]), 0.0f);
                dw |= ((unsigned)val) << (8 * r);
            }
            *(unsigned*)&smem[wr[mc]] = dw;   // q(ca1)
        }
        i32x4 bf[4];
        #pragma unroll
        for (int c = 0; c < 4; ++c) bf[c] = *(const i32x4*)&smem[rds[c]];
        #pragma unroll
        for (int mc = 0; mc < 16; ++mc) {
            i32x4 acc = {0, 0, 0, 0};
            #pragma unroll
            for (int c = 0; c < 4; ++c)
                acc = __builtin_amdgcn_mfma_i32_16x16x64_i8(
                    *(const i32x4*)&smem[rdw[c] + mc * 4096], bf[c], acc, 0, 0, 0);
            const f32x4 cv = *(const f32x4*)&cue[grow * 256 + mc * 16 + quad * 4];
            unsigned dw = 0;
            #pragma unroll
            for (int r = 0; r < 4; ++r) {
                const int v = 4 * mc + r;
                const float n5 = __builtin_amdgcn_fmed3f(
                    fmaf((float)acc[r], f2, e5[v]), 0.0f, 1.0f);
                const float n3 = __builtin_amdgcn_fmed3f(cv[r], 0.0f, 1.0f);
                e5[v] = n5; e3[v] = n3;
                dw |= ((unsigned)fmaf(n3, 127.0f, 0.5f)) << (8 * r);
            }
            *(unsigned*)&smem[wr[mc]] = dw;   // q(ec3)
        }
    }

    // ================= steady state t = 1..98 (no barriers) =================
    for (int t = 1; t <= 98; ++t) {
        const float f2 = ctab[t] * sWc127;
        const float* Ab = &Atab[t * 256 + quad * 64];
        const float* Eb = &Etab[t * 256 + quad * 64];

        i32x4 bf[4];   // q(ec3) B-frags from own scratch (written last iter)
        #pragma unroll
        for (int c = 0; c < 4; ++c) bf[c] = *(const i32x4*)&smem[rds[c]];

        // GEMM1 + e1 per 16-feature chunk; write q(ca1) to scratch
        #pragma unroll
        for (int mc = 0; mc < 16; ++mc) {
            i32x4 acc = {0, 0, 0, 0};
            #pragma unroll
            for (int c = 0; c < 4; ++c)
                acc = __builtin_amdgcn_mfma_i32_16x16x64_i8(
                    *(const i32x4*)&smem[rdv[c] + mc * 4096], bf[c], acc, 0, 0, 0);
            const f32x4 av = *(const f32x4*)&Ab[mc * 4];
            const f32x4 ev = *(const f32x4*)&Eb[mc * 4];
            unsigned dw = 0;
            #pragma unroll
            for (int r = 0; r < 4; ++r) {
                const float e  = __expf((float)acc[r] * negf1);
                const float s  = __builtin_amdgcn_rcpf(1.0f + e);
                const float val = fmaxf(fmaf(av[r], s, ev[r]), 0.0f);
                dw |= ((unsigned)val) << (8 * r);
            }
            *(unsigned*)&smem[wr[mc]] = dw;
        }

        i32x4 cf[4];   // q(ca1) B-frags
        #pragma unroll
        for (int c = 0; c < 4; ++c) cf[c] = *(const i32x4*)&smem[rds[c]];

        // GEMM2 + e2 per chunk; write q(ec3) to scratch
        #pragma unroll
        for (int mc = 0; mc < 16; ++mc) {
            i32x4 acc = {0, 0, 0, 0};
            #pragma unroll
            for (int c = 0; c < 4; ++c)
                acc = __builtin_amdgcn_mfma_i32_16x16x64_i8(
                    *(const i32x4*)&smem[rdw[c] + mc * 4096], cf[c], acc, 0, 0, 0);
            unsigned dw = 0;
            #pragma unroll
            for (int r = 0; r < 4; ++r) {
                const int v = 4 * mc + r;
                const float n5 = __builtin_amdgcn_fmed3f(
                    fmaf((float)acc[r], f2, e5[v]), 0.0f, 1.0f);
                const float n3 = n5 * e3[v];   // both in [0,1]: clip redundant
                e5[v] = n5; e3[v] = n3;
                dw |= ((unsigned)fmaf(n3, 127.0f, 0.5f)) << (8 * r);
            }
            *(unsigned*)&smem[wr[mc]] = dw;
        }
    }

    // ================= t = 99 (peeled): ca1 -> out, fp32 path =================
    {
        const float ct99 = ctab[99];
        const float* Ab = &Atab[99 * 256 + quad * 64];
        const float* Eb = &Etab[99 * 256 + quad * 64];
        i32x4 bf[4];
        #pragma unroll
        for (int c = 0; c < 4; ++c) bf[c] = *(const i32x4*)&smem[rds[c]];
        float p0 = 0.f, p1 = 0.f;
        #pragma unroll
        for (int mc = 0; mc < 16; ++mc) {
            i32x4 acc = {0, 0, 0, 0};
            #pragma unroll
            for (int c = 0; c < 4; ++c)
                acc = __builtin_amdgcn_mfma_i32_16x16x64_i8(
                    *(const i32x4*)&smem[rdv[c] + mc * 4096], bf[c], acc, 0, 0, 0);
            const f32x4 av = *(const f32x4*)&Ab[mc * 4];
            const f32x4 ev = *(const f32x4*)&Eb[mc * 4];
            const int f0 = mc * 16 + quad * 4;
            const f32x4 w0 = *(const f32x4*)&Wact[f0 * 2];       // f2,f2+1 for r=0,1
            const f32x4 w1 = *(const f32x4*)&Wact[f0 * 2 + 4];   // r=2,3
            #pragma unroll
            for (int r = 0; r < 4; ++r) {
                const float e  = __expf((float)acc[r] * negf1);
                const float s  = __builtin_amdgcn_rcpf(1.0f + e);
                const float ca1 = fmaxf(fmaf(av[r], s, ev[r]) - 0.5f, 0.0f) * ct99;
                const float wa = (r < 2) ? ((r == 0) ? w0[0] : w0[2])
                                         : ((r == 2) ? w1[0] : w1[2]);
                const float wb = (r < 2) ? ((r == 0) ? w0[1] : w0[3])
                                         : ((r == 2) ? w1[1] : w1[3]);
                p0 = fmaf(ca1, wa, p0);
                p1 = fmaf(ca1, wb, p1);
            }
        }
        p0 += __shfl_xor(p0, 16); p0 += __shfl_xor(p0, 32);
        p1 += __shfl_xor(p1, 16); p1 += __shfl_xor(p1, 32);
        if (quad == 0) {
            f32x2 o; o[0] = p0; o[1] = p1;
            *(f32x2*)&out[grow * 2] = o;
        }
    }
}

extern "C" void kernel_launch(void* const* d_in, const int* in_sizes, int n_in,
                              void* d_out, int out_size, void* d_ws, size_t ws_size,
                              hipStream_t stream) {
    const float* cue      = (const float*)d_in[0];
    const float* ec5_init = (const float*)d_in[1];
    const float* Wapical  = (const float*)d_in[2];
    const float* Wbasal   = (const float*)d_in[3];
    const float* Wca1ec5  = (const float*)d_in[4];
    const float* Waction  = (const float*)d_in[5];
    const float* ca1bias  = (const float*)d_in[6];
    float* out  = (float*)d_out;
    float* Atab = (float*)d_ws;              // 100*256 f32
    float* Etab = Atab + 25600;              // 100*256 f32
    float* ctab = Etab + 25600;              // 100 f32   (total ~205 KB of ws)

    basal2_kernel<<<100, 256, 0, stream>>>(Wbasal, ca1bias, Atab, Etab, ctab);
    rnn_kernel<<<256, 512, 0, stream>>>(cue, ec5_init, Wapical, Wca1ec5, Waction,
                                        Atab, Etab, ctab, out);
}